// Round 6
// baseline (62.994 us; speedup 1.0000x reference)
//
#include <hip/hip_runtime.h>

// SpatialTransformer 2D->2D bilinear sampling.
// Pipeline (3 graph nodes):
//   hipMemsetAsync : zero binCnt[NBINS]+ovCnt
//   k_scatter      : single-pass capacity-binned scatter; pre-gathers clamped
//                    (x,y) float2 into bin-sorted order
//   st_bins        : PERSISTENT blocks (256 x 512thr, 1/CU). Each owns 15
//                    XCD-contiguous bins. Double-buffered 2x48KB LDS tiles via
//                    async global_load_lds with counted s_waitcnt vmcnt(6)
//                    (prefetch survives raw s_barrier). All meta staged to LDS
//                    at prologue. Nontemporal 2KB/point output stores.

typedef float f32x4 __attribute__((ext_vector_type(4)));

#define GLOBAL_AS __attribute__((address_space(1)))
#define LDS_AS    __attribute__((address_space(3)))

constexpr int NR   = 4;
constexpr int FH   = 90;
constexpr int FW   = 160;
constexpr int FDIM = 512;
constexpr int NV   = 120 * 160;    // 19200
constexpr int NPTS = NR * NV;      // 76800
constexpr int C4   = FDIM / 4;     // 128

constexpr int BY   = 3;
constexpr int BX   = 5;
constexpr int NGY  = FH / BY;      // 30
constexpr int NGX  = FW / BX;      // 32
constexpr int NBINS = NR * NGY * NGX;  // 3840
constexpr int SY   = BY + 1;       // 4
constexpr int SX   = BX + 1;       // 6
constexpr int SCELLS = SY * SX;    // 24 cells -> 48 KB / buffer

constexpr int CAP   = 48;          // per-bin capacity (lambda = 20)
constexpr int OVCAP = 4096;
constexpr int TPB   = 512;
constexpr int NBLK  = 256;         // persistent blocks, 1 per CU
constexpr int BPB   = NBINS / NBLK;    // 15 bins per block
constexpr int LDSX4 = SCELLS * C4;     // 3072 f32x4 per buffer

__global__ void k_scatter(const float* __restrict__ imx, const float* __restrict__ imy,
                          int* __restrict__ binCnt, int* __restrict__ ovCnt,
                          int* __restrict__ perm, float2* __restrict__ sXY,
                          int* __restrict__ ovList) {
    int pt = blockIdx.x * blockDim.x + threadIdx.x;
    if (pt >= NPTS) return;
    int r = pt / NV;
    float x = fminf(fmaxf(imx[pt], 0.0f), (float)(FW - 1));
    float y = fminf(fmaxf(imy[pt], 0.0f), (float)(FH - 1));
    int b = (r * NGY + (int)floorf(y) / BY) * NGX + (int)floorf(x) / BX;
    int slot = atomicAdd(&binCnt[b], 1);
    if (slot < CAP) {
        int idx = b * CAP + slot;
        perm[idx] = pt;
        sXY[idx] = make_float2(x, y);
    } else {
        int o = atomicAdd(ovCnt, 1);
        if (o < OVCAP) ovList[o] = pt;
    }
}

__device__ __forceinline__ f32x4 lerp4(f32x4 A, f32x4 B, f32x4 C, f32x4 D,
                                       float wa, float wb, float wc, float wd) {
    return wa * A + wb * B + wc * C + wd * D;
}

__device__ __forceinline__ void weights_and_cells(float x, float y,
                                                  int& x0, int& x1, int& y0, int& y1,
                                                  float& wa, float& wb, float& wc, float& wd) {
    float x0f = floorf(x), y0f = floorf(y);
    x0 = (int)x0f; y0 = (int)y0f;
    x1 = min(x0 + 1, FW - 1);
    y1 = min(y0 + 1, FH - 1);
    float wx1 = (float)x1 - x;
    float wx0 = x - x0f;
    float wy1 = (float)y1 - y;
    float wy0 = y - y0f;
    wa = wx1 * wy1; wb = wx1 * wy0; wc = wx0 * wy1; wd = wx0 * wy0;
}

__device__ __forceinline__ void stage_bin(const f32x4* __restrict__ in4,
                                          f32x4* ldsbuf, int b, int tid) {
    int r   = b / (NGY * NGX);
    int by0 = (b / NGX % NGY) * BY;
    int bx0 = (b % NGX) * BX;
    #pragma unroll
    for (int i = 0; i < LDSX4 / TPB; ++i) {   // 6 x 16B per thread; per wave:
        int idx  = tid + i * TPB;             // wave-uniform LDS base + lane*16
        int cell = idx >> 7;
        int c4   = idx & (C4 - 1);
        int ry   = cell / SX;
        int rx   = cell - ry * SX;
        int gy   = min(by0 + ry, FH - 1);
        int gx   = min(bx0 + rx, FW - 1);
        __builtin_amdgcn_global_load_lds(
            (const GLOBAL_AS void*)(in4 + (size_t)((r * FH + gy) * FW + gx) * C4 + c4),
            (LDS_AS void*)&ldsbuf[idx], 16, 0, 0);
    }
}

__global__ __launch_bounds__(TPB) void st_bins(
    const float* __restrict__ inp,
    const int* __restrict__ binCnt,
    const int* __restrict__ ovCnt,
    const int* __restrict__ perm,
    const float2* __restrict__ sXY,
    const int* __restrict__ ovList,
    const float* __restrict__ imx,
    const float* __restrict__ imy,
    float* __restrict__ out)
{
    __shared__ f32x4  lds[2 * LDSX4];        // 96 KB ping-pong tile buffers
    __shared__ int    pmS[BPB * CAP];        // 720 ints
    __shared__ float2 xyS[BPB * CAP];        // 720 float2
    __shared__ int    cntS[BPB];

    int p   = blockIdx.x;
    int xcd = p & 7, slot = p >> 3;          // chunked XCD assignment:
    int l0  = xcd * (NBINS / 8) + slot * BPB;// same-XCD blocks cover contiguous bins

    int tid = threadIdx.x;
    const f32x4* in4 = (const f32x4*)inp;

    // Prologue: stage ALL meta (contiguous ranges -> coalesced), then tile 0.
    int mbase = l0 * CAP;
    for (int i = tid; i < BPB * CAP; i += TPB) {
        pmS[i] = perm[mbase + i];
        xyS[i] = sXY[mbase + i];
    }
    if (tid < BPB) cntS[tid] = min(binCnt[l0 + tid], CAP);
    stage_bin(in4, &lds[0], l0, tid);

    int g  = tid >> 7;            // 4 groups of 128 threads
    int c4 = tid & (C4 - 1);
    f32x4* out4 = (f32x4*)out;
    int cur = 0;

    for (int k = 0; k < BPB; ++k) {
        int b = l0 + k;
        if (k + 1 < BPB)
            stage_bin(in4, &lds[(cur ^ 1) * LDSX4], b + 1, tid);

        // Wait: current buffer's 6 loads are the oldest outstanding VMEM ops;
        // vmcnt retires in order, so vmcnt(6) (= the 6 next-bin loads still in
        // flight) guarantees they are done. lgkmcnt(0) publishes meta ds_writes.
        if (k + 1 < BPB)
            asm volatile("s_waitcnt vmcnt(6) lgkmcnt(0)" ::: "memory");
        else
            asm volatile("s_waitcnt vmcnt(0) lgkmcnt(0)" ::: "memory");
        __builtin_amdgcn_sched_barrier(0);
        __builtin_amdgcn_s_barrier();
        __builtin_amdgcn_sched_barrier(0);

        // Compute bin b from lds[cur].
        {
            const f32x4* buf = &lds[cur * LDSX4];
            int by0 = (b / NGX % NGY) * BY;
            int bx0 = (b % NGX) * BX;
            int cnt  = cntS[k];
            int mofs = k * CAP;

            int i = g;
            for (; i + 4 < cnt; i += 8) {
                int    ptA = pmS[mofs + i];
                float2 cA  = xyS[mofs + i];
                int    ptB = pmS[mofs + i + 4];
                float2 cB  = xyS[mofs + i + 4];

                int x0A, x1A, y0A, y1A, x0B, x1B, y0B, y1B;
                float waA, wbA, wcA, wdA, waB, wbB, wcB, wdB;
                weights_and_cells(cA.x, cA.y, x0A, x1A, y0A, y1A, waA, wbA, wcA, wdA);
                weights_and_cells(cB.x, cB.y, x0B, x1B, y0B, y1B, waB, wbB, wcB, wdB);

                f32x4 Aa = buf[(((y0A - by0) * SX + (x0A - bx0)) << 7) + c4];
                f32x4 Ab = buf[(((y1A - by0) * SX + (x0A - bx0)) << 7) + c4];
                f32x4 Ac = buf[(((y0A - by0) * SX + (x1A - bx0)) << 7) + c4];
                f32x4 Ad = buf[(((y1A - by0) * SX + (x1A - bx0)) << 7) + c4];
                f32x4 Ba = buf[(((y0B - by0) * SX + (x0B - bx0)) << 7) + c4];
                f32x4 Bb = buf[(((y1B - by0) * SX + (x0B - bx0)) << 7) + c4];
                f32x4 Bc = buf[(((y0B - by0) * SX + (x1B - bx0)) << 7) + c4];
                f32x4 Bd = buf[(((y1B - by0) * SX + (x1B - bx0)) << 7) + c4];

                __builtin_nontemporal_store(lerp4(Aa, Ab, Ac, Ad, waA, wbA, wcA, wdA),
                                            out4 + (size_t)ptA * C4 + c4);
                __builtin_nontemporal_store(lerp4(Ba, Bb, Bc, Bd, waB, wbB, wcB, wdB),
                                            out4 + (size_t)ptB * C4 + c4);
            }
            if (i < cnt) {
                int    pt = pmS[mofs + i];
                float2 cc = xyS[mofs + i];
                int x0, x1, y0, y1; float wa, wb, wc, wd;
                weights_and_cells(cc.x, cc.y, x0, x1, y0, y1, wa, wb, wc, wd);
                f32x4 A = buf[(((y0 - by0) * SX + (x0 - bx0)) << 7) + c4];
                f32x4 B = buf[(((y1 - by0) * SX + (x0 - bx0)) << 7) + c4];
                f32x4 C = buf[(((y0 - by0) * SX + (x1 - bx0)) << 7) + c4];
                f32x4 D = buf[(((y1 - by0) * SX + (x1 - bx0)) << 7) + c4];
                __builtin_nontemporal_store(lerp4(A, B, C, D, wa, wb, wc, wd),
                                            out4 + (size_t)pt * C4 + c4);
            }
        }

        // All waves must finish reading lds[cur] before next iter overwrites it.
        __builtin_amdgcn_sched_barrier(0);
        __builtin_amdgcn_s_barrier();
        cur ^= 1;
    }

    // Cold path: overflow points (slot >= CAP) via direct global gather.
    int ov = min(*ovCnt, OVCAP);
    for (int j = p; j < ov; j += NBLK) {
        if (g != 0) continue;
        int pt = ovList[j];
        int rr = pt / NV;
        float x = fminf(fmaxf(imx[pt], 0.0f), (float)(FW - 1));
        float y = fminf(fmaxf(imy[pt], 0.0f), (float)(FH - 1));
        int x0, x1, y0, y1; float wa, wb, wc, wd;
        weights_and_cells(x, y, x0, x1, y0, y1, wa, wb, wc, wd);
        int rb = rr * FH;
        f32x4 A = in4[(size_t)((rb + y0) * FW + x0) * C4 + c4];
        f32x4 B = in4[(size_t)((rb + y1) * FW + x0) * C4 + c4];
        f32x4 C = in4[(size_t)((rb + y0) * FW + x1) * C4 + c4];
        f32x4 D = in4[(size_t)((rb + y1) * FW + x1) * C4 + c4];
        __builtin_nontemporal_store(lerp4(A, B, C, D, wa, wb, wc, wd),
                                    out4 + (size_t)pt * C4 + c4);
    }
}

// Fallback (workspace too small): unsorted direct kernel.
__global__ __launch_bounds__(256) void st_bilinear_direct(
    const float* __restrict__ inp,
    const float* __restrict__ imx,
    const float* __restrict__ imy,
    float* __restrict__ out)
{
    int gid = blockIdx.x * blockDim.x + threadIdx.x;
    int pt = gid >> 7;
    int c4 = gid & (C4 - 1);
    if (pt >= NPTS) return;
    int r = pt / NV;
    float x = fminf(fmaxf(imx[pt], 0.0f), (float)(FW - 1));
    float y = fminf(fmaxf(imy[pt], 0.0f), (float)(FH - 1));
    int x0, x1, y0, y1; float wa, wb, wc, wd;
    weights_and_cells(x, y, x0, x1, y0, y1, wa, wb, wc, wd);
    const f32x4* base = (const f32x4*)inp;
    int rb = r * FH;
    f32x4 a = base[(size_t)((rb + y0) * FW + x0) * C4 + c4];
    f32x4 b = base[(size_t)((rb + y1) * FW + x0) * C4 + c4];
    f32x4 c = base[(size_t)((rb + y0) * FW + x1) * C4 + c4];
    f32x4 d = base[(size_t)((rb + y1) * FW + x1) * C4 + c4];
    ((f32x4*)out)[(size_t)pt * C4 + c4] = lerp4(a, b, c, d, wa, wb, wc, wd);
}

extern "C" void kernel_launch(void* const* d_in, const int* in_sizes, int n_in,
                              void* d_out, int out_size, void* d_ws, size_t ws_size,
                              hipStream_t stream) {
    const float* inp = (const float*)d_in[0];
    const float* imx = (const float*)d_in[1];
    const float* imy = (const float*)d_in[2];
    float* out = (float*)d_out;

    // ws: binCnt[NBINS] | ovCnt[1] | perm[NBINS*CAP] | sXY[NBINS*CAP] float2 | ovList
    size_t need = (size_t)(NBINS + 1 + NBINS * CAP + OVCAP) * sizeof(int)
                + (size_t)NBINS * CAP * sizeof(float2);

    if (ws_size < need) {
        int nblocks = (NPTS * C4) / 256;
        hipLaunchKernelGGL(st_bilinear_direct, dim3(nblocks), dim3(256), 0, stream,
                           inp, imx, imy, out);
        return;
    }

    int*    binCnt = (int*)d_ws;
    int*    ovCnt  = binCnt + NBINS;
    int*    perm   = ovCnt + 1;
    float2* sXY    = (float2*)(perm + (size_t)NBINS * CAP);
    int*    ovList = (int*)(sXY + (size_t)NBINS * CAP);

    hipMemsetAsync(binCnt, 0, (NBINS + 1) * sizeof(int), stream);
    hipLaunchKernelGGL(k_scatter, dim3((NPTS + 255) / 256), dim3(256), 0, stream,
                       imx, imy, binCnt, ovCnt, perm, sXY, ovList);
    hipLaunchKernelGGL(st_bins, dim3(NBLK), dim3(TPB), 0, stream,
                       inp, binCnt, ovCnt, perm, sXY, ovList, imx, imy, out);
}

// Round 7
// 58.598 us; speedup vs baseline: 1.0750x; 1.0750x over previous
//
#include <hip/hip_runtime.h>

// SpatialTransformer 2D->2D bilinear sampling.
// Pipeline (3 graph nodes):
//   hipMemsetAsync : zero binCnt[NBINS]+ovCnt
//   k_scatter      : single-pass capacity-binned scatter; pre-gathers clamped
//                    (x,y) float2 into bin-sorted order
//   st_bins        : one 512-thread block per (view, 2x5-cell) bin; stages the
//                    3x6-cell halo footprint (36 KB) into LDS via async
//                    global_load_lds -> 4 blocks/CU = 32 waves/CU (max TLP).
//                    Serves all 4-corner gathers from LDS, nontemporal stores.
//                    Overflow points (slot>=CAP) via direct global gather.

typedef float f32x4 __attribute__((ext_vector_type(4)));

#define GLOBAL_AS __attribute__((address_space(1)))
#define LDS_AS    __attribute__((address_space(3)))

constexpr int NR   = 4;
constexpr int FH   = 90;
constexpr int FW   = 160;
constexpr int FDIM = 512;
constexpr int NV   = 120 * 160;    // 19200
constexpr int NPTS = NR * NV;      // 76800
constexpr int C4   = FDIM / 4;     // 128

constexpr int BY   = 2;            // bin height in cells
constexpr int BX   = 5;            // bin width in cells
constexpr int NGY  = FH / BY;      // 45
constexpr int NGX  = FW / BX;      // 32
constexpr int NBINS = NR * NGY * NGX;  // 5760 (divisible by 8)
constexpr int SY   = BY + 1;       // 3 staged rows
constexpr int SX   = BX + 1;       // 6 staged cols
constexpr int SCELLS = SY * SX;    // 18 cells -> 36 KB LDS
constexpr int LDSX4 = SCELLS * C4; // 2304 f32x4

constexpr int CAP   = 32;          // per-bin capacity (lambda = 13.3)
constexpr int OVCAP = 4096;
constexpr int TPB   = 512;

__global__ void k_scatter(const float* __restrict__ imx, const float* __restrict__ imy,
                          int* __restrict__ binCnt, int* __restrict__ ovCnt,
                          int* __restrict__ perm, float2* __restrict__ sXY,
                          int* __restrict__ ovList) {
    int pt = blockIdx.x * blockDim.x + threadIdx.x;
    if (pt >= NPTS) return;
    int r = pt / NV;
    float x = fminf(fmaxf(imx[pt], 0.0f), (float)(FW - 1));
    float y = fminf(fmaxf(imy[pt], 0.0f), (float)(FH - 1));
    int b = (r * NGY + (int)floorf(y) / BY) * NGX + (int)floorf(x) / BX;
    int slot = atomicAdd(&binCnt[b], 1);
    if (slot < CAP) {
        int idx = b * CAP + slot;
        perm[idx] = pt;
        sXY[idx] = make_float2(x, y);
    } else {
        int o = atomicAdd(ovCnt, 1);
        if (o < OVCAP) ovList[o] = pt;
    }
}

__device__ __forceinline__ f32x4 lerp4(f32x4 A, f32x4 B, f32x4 C, f32x4 D,
                                       float wa, float wb, float wc, float wd) {
    return wa * A + wb * B + wc * C + wd * D;
}

__device__ __forceinline__ void weights_and_cells(float x, float y,
                                                  int& x0, int& x1, int& y0, int& y1,
                                                  float& wa, float& wb, float& wc, float& wd) {
    float x0f = floorf(x), y0f = floorf(y);
    x0 = (int)x0f; y0 = (int)y0f;
    x1 = min(x0 + 1, FW - 1);
    y1 = min(y0 + 1, FH - 1);
    float wx1 = (float)x1 - x;
    float wx0 = x - x0f;
    float wy1 = (float)y1 - y;
    float wy0 = y - y0f;
    wa = wx1 * wy1; wb = wx1 * wy0; wc = wx0 * wy1; wd = wx0 * wy0;
}

__global__ __launch_bounds__(TPB) void st_bins(
    const float* __restrict__ inp,
    const int* __restrict__ binCnt,
    const int* __restrict__ ovCnt,
    const int* __restrict__ perm,
    const float2* __restrict__ sXY,
    const int* __restrict__ ovList,
    const float* __restrict__ imx,
    const float* __restrict__ imy,
    float* __restrict__ out)
{
    __shared__ f32x4  lds[LDSX4];    // 36 KB halo tile
    __shared__ int    pmS[CAP];
    __shared__ float2 xyS[CAP];

    int p = blockIdx.x;
    int b = (p & 7) * (NBINS >> 3) + (p >> 3);   // chunked XCD swizzle

    int r   = b / (NGY * NGX);
    int by0 = (b / NGX % NGY) * BY;
    int bx0 = (b % NGX) * BX;
    int tid = threadIdx.x;

    const f32x4* in4 = (const f32x4*)inp;
    int cnt  = min(binCnt[b], CAP);
    int base = b * CAP;

    // Async staging: 2304 f32x4 = 4.5 x 512 threads; iteration 4's guard
    // (tid < 256) is wave-uniform (4 full waves active, 4 fully inactive).
    #pragma unroll
    for (int i = 0; i < 5; ++i) {
        int idx = tid + i * TPB;
        if (idx < LDSX4) {
            int cell = idx >> 7;
            int c4   = idx & (C4 - 1);
            int ry   = cell / SX;
            int rx   = cell - ry * SX;
            int gy   = min(by0 + ry, FH - 1);   // edge bins: duplicate last row/col
            int gx   = min(bx0 + rx, FW - 1);
            __builtin_amdgcn_global_load_lds(
                (const GLOBAL_AS void*)(in4 + (size_t)((r * FH + gy) * FW + gx) * C4 + c4),
                (LDS_AS void*)&lds[idx], 16, 0, 0);
        }
    }
    // Stage point metadata (overlaps with async tile staging).
    if (tid < cnt) {
        pmS[tid] = perm[base + tid];
        xyS[tid] = sXY[base + tid];
    }
    __syncthreads();   // drains vmcnt(0): global_load_lds writes are visible

    int g  = tid >> 7;            // 4 groups of 128 threads
    int c4 = tid & (C4 - 1);
    f32x4* out4 = (f32x4*)out;

    int i = g;
    // 2-point unrolled loop per group: 8 LDS reads in flight.
    for (; i + 4 < cnt; i += 8) {
        int    ptA = pmS[i];
        float2 cA  = xyS[i];
        int    ptB = pmS[i + 4];
        float2 cB  = xyS[i + 4];

        int x0A, x1A, y0A, y1A, x0B, x1B, y0B, y1B;
        float waA, wbA, wcA, wdA, waB, wbB, wcB, wdB;
        weights_and_cells(cA.x, cA.y, x0A, x1A, y0A, y1A, waA, wbA, wcA, wdA);
        weights_and_cells(cB.x, cB.y, x0B, x1B, y0B, y1B, waB, wbB, wcB, wdB);

        f32x4 Aa = lds[(((y0A - by0) * SX + (x0A - bx0)) << 7) + c4];
        f32x4 Ab = lds[(((y1A - by0) * SX + (x0A - bx0)) << 7) + c4];
        f32x4 Ac = lds[(((y0A - by0) * SX + (x1A - bx0)) << 7) + c4];
        f32x4 Ad = lds[(((y1A - by0) * SX + (x1A - bx0)) << 7) + c4];
        f32x4 Ba = lds[(((y0B - by0) * SX + (x0B - bx0)) << 7) + c4];
        f32x4 Bb = lds[(((y1B - by0) * SX + (x0B - bx0)) << 7) + c4];
        f32x4 Bc = lds[(((y0B - by0) * SX + (x1B - bx0)) << 7) + c4];
        f32x4 Bd = lds[(((y1B - by0) * SX + (x1B - bx0)) << 7) + c4];

        __builtin_nontemporal_store(lerp4(Aa, Ab, Ac, Ad, waA, wbA, wcA, wdA),
                                    out4 + (size_t)ptA * C4 + c4);
        __builtin_nontemporal_store(lerp4(Ba, Bb, Bc, Bd, waB, wbB, wcB, wdB),
                                    out4 + (size_t)ptB * C4 + c4);
    }
    if (i < cnt) {
        int    pt = pmS[i];
        float2 cc = xyS[i];
        int x0, x1, y0, y1; float wa, wb, wc, wd;
        weights_and_cells(cc.x, cc.y, x0, x1, y0, y1, wa, wb, wc, wd);
        f32x4 A = lds[(((y0 - by0) * SX + (x0 - bx0)) << 7) + c4];
        f32x4 B = lds[(((y1 - by0) * SX + (x0 - bx0)) << 7) + c4];
        f32x4 C = lds[(((y0 - by0) * SX + (x1 - bx0)) << 7) + c4];
        f32x4 D = lds[(((y1 - by0) * SX + (x1 - bx0)) << 7) + c4];
        __builtin_nontemporal_store(lerp4(A, B, C, D, wa, wb, wc, wd),
                                    out4 + (size_t)pt * C4 + c4);
    }

    // Cold path: overflow points (slot >= CAP) via direct global gather.
    int ov = min(*ovCnt, OVCAP);
    for (int j = b; j < ov; j += NBINS) {
        if (g != 0) continue;
        int pt = ovList[j];
        int rr = pt / NV;
        float x = fminf(fmaxf(imx[pt], 0.0f), (float)(FW - 1));
        float y = fminf(fmaxf(imy[pt], 0.0f), (float)(FH - 1));
        int x0, x1, y0, y1; float wa, wb, wc, wd;
        weights_and_cells(x, y, x0, x1, y0, y1, wa, wb, wc, wd);
        int rb = rr * FH;
        f32x4 A = in4[(size_t)((rb + y0) * FW + x0) * C4 + c4];
        f32x4 B = in4[(size_t)((rb + y1) * FW + x0) * C4 + c4];
        f32x4 C = in4[(size_t)((rb + y0) * FW + x1) * C4 + c4];
        f32x4 D = in4[(size_t)((rb + y1) * FW + x1) * C4 + c4];
        __builtin_nontemporal_store(lerp4(A, B, C, D, wa, wb, wc, wd),
                                    out4 + (size_t)pt * C4 + c4);
    }
}

// Fallback (workspace too small): unsorted direct kernel.
__global__ __launch_bounds__(256) void st_bilinear_direct(
    const float* __restrict__ inp,
    const float* __restrict__ imx,
    const float* __restrict__ imy,
    float* __restrict__ out)
{
    int gid = blockIdx.x * blockDim.x + threadIdx.x;
    int pt = gid >> 7;
    int c4 = gid & (C4 - 1);
    if (pt >= NPTS) return;
    int r = pt / NV;
    float x = fminf(fmaxf(imx[pt], 0.0f), (float)(FW - 1));
    float y = fminf(fmaxf(imy[pt], 0.0f), (float)(FH - 1));
    int x0, x1, y0, y1; float wa, wb, wc, wd;
    weights_and_cells(x, y, x0, x1, y0, y1, wa, wb, wc, wd);
    const f32x4* base = (const f32x4*)inp;
    int rb = r * FH;
    f32x4 a = base[(size_t)((rb + y0) * FW + x0) * C4 + c4];
    f32x4 b = base[(size_t)((rb + y1) * FW + x0) * C4 + c4];
    f32x4 c = base[(size_t)((rb + y0) * FW + x1) * C4 + c4];
    f32x4 d = base[(size_t)((rb + y1) * FW + x1) * C4 + c4];
    ((f32x4*)out)[(size_t)pt * C4 + c4] = lerp4(a, b, c, d, wa, wb, wc, wd);
}

extern "C" void kernel_launch(void* const* d_in, const int* in_sizes, int n_in,
                              void* d_out, int out_size, void* d_ws, size_t ws_size,
                              hipStream_t stream) {
    const float* inp = (const float*)d_in[0];
    const float* imx = (const float*)d_in[1];
    const float* imy = (const float*)d_in[2];
    float* out = (float*)d_out;

    // ws: binCnt[NBINS] | ovCnt[1] | perm[NBINS*CAP] | sXY[NBINS*CAP] float2 | ovList
    size_t need = (size_t)(NBINS + 1 + NBINS * CAP + OVCAP) * sizeof(int)
                + (size_t)NBINS * CAP * sizeof(float2);   // ~2.25 MB

    if (ws_size < need) {
        int nblocks = (NPTS * C4) / 256;
        hipLaunchKernelGGL(st_bilinear_direct, dim3(nblocks), dim3(256), 0, stream,
                           inp, imx, imy, out);
        return;
    }

    int*    binCnt = (int*)d_ws;
    int*    ovCnt  = binCnt + NBINS;
    int*    perm   = ovCnt + 1;
    float2* sXY    = (float2*)(perm + (size_t)NBINS * CAP);
    int*    ovList = (int*)(sXY + (size_t)NBINS * CAP);

    hipMemsetAsync(binCnt, 0, (NBINS + 1) * sizeof(int), stream);
    hipLaunchKernelGGL(k_scatter, dim3((NPTS + 255) / 256), dim3(256), 0, stream,
                       imx, imy, binCnt, ovCnt, perm, sXY, ovList);
    hipLaunchKernelGGL(st_bins, dim3(NBINS), dim3(TPB), 0, stream,
                       inp, binCnt, ovCnt, perm, sXY, ovList, imx, imy, out);
}